// Round 5
// baseline (90.056 us; speedup 1.0000x reference)
//
#include <hip/hip_runtime.h>
#include <stdint.h>

// Problem constants (match reference)
#define Bdim 64
#define Tdim 1024
#define Edim 128
#define Cdim 5
#define Fdim 64
#define Hpad 2      // C/2
#define Kdim (Cdim * Edim)   // 640

// Tile geometry
#define TTILE 32                 // t-positions per workgroup (32 -> 8 acc VGPRs, occupancy up)
#define XROWS (TTILE + Cdim - 1) // 36 rows: t0-2 .. t0+33
#define LDSTR (Edim + 8)         // 136 shorts/row

typedef __attribute__((ext_vector_type(8))) short short8;     // 8 bf16 = 4 VGPRs (MFMA frag)
typedef __attribute__((ext_vector_type(4))) float float4v;
typedef __attribute__((ext_vector_type(4))) unsigned short ushort4v;

__device__ __forceinline__ unsigned short f2bf(float f) {
    // round-to-nearest-even fp32 -> bf16 (inputs finite randn; no NaN path needed)
    union { float f; uint32_t u; } v; v.f = f;
    uint32_t u = v.u;
    u += 0x7fffu + ((u >> 16) & 1u);
    return (unsigned short)(u >> 16);
}

// ---- Pre-kernel: W fp32 [F, C*E] -> bf16, swizzled into MFMA B-fragment order:
//   Wbf[(((c*4 + kk)*4 + wave)*4 + quad)*128 + m16*8 + j]
// where f = wave*16 + m16, k = c*128 + kk*32 + quad*8 + j.
// A wave's per-(c,kk) fragment load is 1 KB fully contiguous (16 B/lane), L2-hot.
__global__ void convert_W(const float* __restrict__ W, unsigned short* __restrict__ Wbf) {
    int i = blockIdx.x * 256 + threadIdx.x;      // float4 slot, 10240 total
    if (i >= (Fdim * Kdim) / 4) return;
    const int e0 = i * 4;                        // flat input index, 4-aligned
    const int f  = e0 / Kdim;
    const int k  = e0 % Kdim;
    const int c    = k / Edim;
    const int kin  = k % Edim;
    const int kk   = kin / 32;
    const int q8   = kin % 32;
    const int quad = q8 / 8;
    const int j0   = q8 % 8;                     // 0 or 4
    float4v v = ((const float4v*)W)[i];
    ushort4v o = { f2bf(v.x), f2bf(v.y), f2bf(v.z), f2bf(v.w) };
    const int dst = (((c * 4 + kk) * 4 + (f >> 4)) * 4 + quad) * 128 + (f & 15) * 8 + j0;
    *(ushort4v*)&Wbf[dst] = o;
}

// ---- Main kernel: one block = 32 t-positions of one batch row; 4 waves split F.
// Single barrier; B-frags coalesced from swizzled Wbf; A from LDS bf16 x-window.
// launch_bounds(256,6): 85-VGPR cap -> 24 waves/CU resident (vs 16 at TTILE=64).
__global__ __launch_bounds__(256, 6)
void qa_cnn_main(const float* __restrict__ x, const unsigned short* __restrict__ Wbf,
                 const float* __restrict__ bias, float* __restrict__ out) {
    __shared__ __align__(16) unsigned short sX[XROWS * LDSTR]; // 9,792 B

    const int tid = threadIdx.x;
    const int tt  = blockIdx.x;   // 0..31
    const int b   = blockIdx.y;   // 0..63
    const int t0  = tt * TTILE;

    // Stage x window: rows t0-2 .. t0+33, fp32 -> bf16, zero-pad T edges.
    {
        const int nslots = XROWS * (Edim / 4);  // 36*32 = 1152 float4 slots
        for (int idx = tid; idx < nslots; idx += 256) {
            const int row = idx >> 5;
            const int c4  = idx & 31;
            const int gt  = t0 - Hpad + row;
            float4v v = {0.f, 0.f, 0.f, 0.f};
            if (gt >= 0 && gt < Tdim) {
                v = *(const float4v*)(x + ((size_t)b * Tdim + gt) * Edim + c4 * 4);
            }
            ushort4v o = { f2bf(v.x), f2bf(v.y), f2bf(v.z), f2bf(v.w) };
            *(ushort4v*)&sX[row * LDSTR + c4 * 4] = o;
        }
    }

    const int wave = tid >> 6;     // 0..3 -> this wave's 16-f slice
    const int lane = tid & 63;
    const int m16  = lane & 15;
    const int quad = lane >> 4;

    // Swizzled fragment base: per (c,kk) stride = 2048 shorts.
    const unsigned short* wfrag = Wbf + wave * 512 + quad * 128 + m16 * 8;

    float4v acc[2];
    acc[0] = (float4v){0.f, 0.f, 0.f, 0.f};
    acc[1] = (float4v){0.f, 0.f, 0.f, 0.f};

    __syncthreads();   // the only barrier

    #pragma unroll
    for (int c = 0; c < Cdim; ++c) {
        short8 bfrag[4];
        #pragma unroll
        for (int kk = 0; kk < 4; ++kk)
            bfrag[kk] = *(const short8*)(wfrag + (c * 4 + kk) * 2048);

        #pragma unroll
        for (int kk = 0; kk < 4; ++kk) {
            const int kcol = kk * 32 + quad * 8;
            #pragma unroll
            for (int mt = 0; mt < 2; ++mt) {
                // A[m = m16][k], row in sX shifted by tap c
                const short8 a = *(const short8*)&sX[(c + mt * 16 + m16) * LDSTR + kcol];
                acc[mt] = __builtin_amdgcn_mfma_f32_16x16x32_bf16(a, bfrag[kk], acc[mt], 0, 0, 0);
            }
        }
    }

    // Epilogue: D col(n)=lane&15 -> f, row(m)=quad*4+reg -> t. 4 consecutive t/lane.
    const int f  = wave * 16 + m16;
    const float bv = bias[f];
    float* orow = out + ((size_t)b * Fdim + f) * Tdim + t0 + quad * 4;
    #pragma unroll
    for (int mt = 0; mt < 2; ++mt) {
        float4v v = acc[mt];
        v.x += bv; v.y += bv; v.z += bv; v.w += bv;
        *(float4v*)(orow + mt * 16) = v;
    }
}

extern "C" void kernel_launch(void* const* d_in, const int* in_sizes, int n_in,
                              void* d_out, int out_size, void* d_ws, size_t ws_size,
                              hipStream_t stream) {
    const float* x    = (const float*)d_in[0];   // [B, T, E]
    const float* W    = (const float*)d_in[1];   // [F, C*E]
    const float* bias = (const float*)d_in[2];   // [F]
    float* out = (float*)d_out;                  // [B, F, T]
    unsigned short* Wbf = (unsigned short*)d_ws; // 80 KB swizzled bf16 copy of W

    convert_W<<<dim3((Fdim * Kdim / 4 + 255) / 256), dim3(256), 0, stream>>>(W, Wbf);
    qa_cnn_main<<<dim3(Tdim / TTILE, Bdim), dim3(256), 0, stream>>>(x, Wbf, bias, out);
}

// Round 6
// 87.503 us; speedup vs baseline: 1.0292x; 1.0292x over previous
//
#include <hip/hip_runtime.h>
#include <stdint.h>

// Problem constants (match reference)
#define Bdim 64
#define Tdim 1024
#define Edim 128
#define Cdim 5
#define Fdim 64
#define Hpad 2      // C/2
#define Kdim (Cdim * Edim)   // 640

// Tile geometry (TTILE=64 is the measured sweet spot: 32 -> 90.1us, 64 -> 87.8us,
// 128 -> 97.4us across rounds 1/4/5)
#define TTILE 64                 // t-positions per workgroup
#define XROWS (TTILE + Cdim - 1) // 68 rows: t0-2 .. t0+65
#define LDSTR (Edim + 8)         // 136 shorts/row

typedef __attribute__((ext_vector_type(8))) short short8;     // 8 bf16 = 4 VGPRs (MFMA frag)
typedef __attribute__((ext_vector_type(4))) float float4v;
typedef __attribute__((ext_vector_type(4))) unsigned short ushort4v;

__device__ __forceinline__ unsigned short f2bf(float f) {
    // round-to-nearest-even fp32 -> bf16 (inputs finite randn; no NaN path needed)
    union { float f; uint32_t u; } v; v.f = f;
    uint32_t u = v.u;
    u += 0x7fffu + ((u >> 16) & 1u);
    return (unsigned short)(u >> 16);
}

// ---- Pre-kernel: W fp32 [F, C*E] -> bf16, swizzled into MFMA B-fragment order:
//   Wbf[(((c*4 + kk)*4 + wave)*4 + quad)*128 + m16*8 + j]
// where f = wave*16 + m16, k = c*128 + kk*32 + quad*8 + j.
// Result: a wave's per-(c,kk) fragment load is 1 KB fully contiguous (16 B/lane).
// This swizzle bought -4.5us vs row-major Wbf (R2 92.3 -> R4 87.8).
__global__ void convert_W(const float* __restrict__ W, unsigned short* __restrict__ Wbf) {
    int i = blockIdx.x * 256 + threadIdx.x;      // float4 slot, 10240 total
    if (i >= (Fdim * Kdim) / 4) return;
    const int e0 = i * 4;                        // flat input index, 4-aligned
    const int f  = e0 / Kdim;
    const int k  = e0 % Kdim;
    const int c    = k / Edim;
    const int kin  = k % Edim;
    const int kk   = kin / 32;
    const int q8   = kin % 32;
    const int quad = q8 / 8;
    const int j0   = q8 % 8;                     // 0 or 4 (4 consecutive j share the octet)
    float4v v = ((const float4v*)W)[i];
    ushort4v o = { f2bf(v.x), f2bf(v.y), f2bf(v.z), f2bf(v.w) };
    const int dst = (((c * 4 + kk) * 4 + (f >> 4)) * 4 + quad) * 128 + (f & 15) * 8 + j0;
    *(ushort4v*)&Wbf[dst] = o;
}

// ---- Main kernel: one block = 64 t-positions of one batch row; 4 waves split F.
// Single barrier; B-fragments loaded coalesced from swizzled Wbf (L2-hot, 80 KB);
// A from LDS-staged bf16 x-window shifted by tap index.
__global__ __launch_bounds__(256, 4)
void qa_cnn_main(const float* __restrict__ x, const unsigned short* __restrict__ Wbf,
                 const float* __restrict__ bias, float* __restrict__ out) {
    __shared__ __align__(16) unsigned short sX[XROWS * LDSTR]; // 18,496 B

    const int tid = threadIdx.x;
    const int tt  = blockIdx.x;   // 0..15
    const int b   = blockIdx.y;   // 0..63
    const int t0  = tt * TTILE;

    // Stage x window: rows t0-2 .. t0+65, fp32 -> bf16, zero-pad T edges.
    {
        const int nslots = XROWS * (Edim / 4);  // 68*32 = 2176 float4 slots
        for (int idx = tid; idx < nslots; idx += 256) {
            const int row = idx >> 5;
            const int c4  = idx & 31;
            const int gt  = t0 - Hpad + row;
            float4v v = {0.f, 0.f, 0.f, 0.f};
            if (gt >= 0 && gt < Tdim) {
                v = *(const float4v*)(x + ((size_t)b * Tdim + gt) * Edim + c4 * 4);
            }
            ushort4v o = { f2bf(v.x), f2bf(v.y), f2bf(v.z), f2bf(v.w) };
            *(ushort4v*)&sX[row * LDSTR + c4 * 4] = o;
        }
    }

    const int wave = tid >> 6;     // 0..3 -> this wave's 16-f slice
    const int lane = tid & 63;
    const int m16  = lane & 15;
    const int quad = lane >> 4;

    // Swizzled fragment base: per (c,kk) stride = 4 waves * 4 quads * 128 = 2048 shorts.
    const unsigned short* wfrag = Wbf + wave * 512 + quad * 128 + m16 * 8;

    float4v acc[4];
    #pragma unroll
    for (int mt = 0; mt < 4; ++mt) acc[mt] = (float4v){0.f, 0.f, 0.f, 0.f};

    __syncthreads();   // the only barrier

    #pragma unroll
    for (int c = 0; c < Cdim; ++c) {
        short8 bfrag[4];
        #pragma unroll
        for (int kk = 0; kk < 4; ++kk)
            bfrag[kk] = *(const short8*)(wfrag + (c * 4 + kk) * 2048);

        #pragma unroll
        for (int kk = 0; kk < 4; ++kk) {
            const int kcol = kk * 32 + quad * 8;
            #pragma unroll
            for (int mt = 0; mt < 4; ++mt) {
                // A[m = m16][k], row in sX shifted by tap c
                const short8 a = *(const short8*)&sX[(c + mt * 16 + m16) * LDSTR + kcol];
                acc[mt] = __builtin_amdgcn_mfma_f32_16x16x32_bf16(a, bfrag[kk], acc[mt], 0, 0, 0);
            }
        }
    }

    // Epilogue: D col(n)=lane&15 -> f, row(m)=quad*4+reg -> t. 4 consecutive t/lane.
    const int f  = wave * 16 + m16;
    const float bv = bias[f];
    float* orow = out + ((size_t)b * Fdim + f) * Tdim + t0 + quad * 4;
    #pragma unroll
    for (int mt = 0; mt < 4; ++mt) {
        float4v v = acc[mt];
        v.x += bv; v.y += bv; v.z += bv; v.w += bv;
        *(float4v*)(orow + mt * 16) = v;
    }
}

extern "C" void kernel_launch(void* const* d_in, const int* in_sizes, int n_in,
                              void* d_out, int out_size, void* d_ws, size_t ws_size,
                              hipStream_t stream) {
    const float* x    = (const float*)d_in[0];   // [B, T, E]
    const float* W    = (const float*)d_in[1];   // [F, C*E]
    const float* bias = (const float*)d_in[2];   // [F]
    float* out = (float*)d_out;                  // [B, F, T]
    unsigned short* Wbf = (unsigned short*)d_ws; // 80 KB swizzled bf16 copy of W

    convert_W<<<dim3((Fdim * Kdim / 4 + 255) / 256), dim3(256), 0, stream>>>(W, Wbf);
    qa_cnn_main<<<dim3(Tdim / TTILE, Bdim), dim3(256), 0, stream>>>(x, Wbf, bias, out);
}